// Round 3
// baseline (118.779 us; speedup 1.0000x reference)
//
#include <hip/hip_runtime.h>

// Encode 11x11 hex boards -> (B, 27, 12, 12) one-hot pattern tensor.
// Store-BW-bound: 509.6 MB output. Two-kernel split:
//   k1: boards -> per-cell 9-bit masks in d_ws (9.4 MB)
//   k2: pure store stream, no barriers/LDS, one board per block.

#define G 8  // boards per block in k1

typedef float f4 __attribute__((ext_vector_type(4)));

// need[p] = (1<<v0) | (1<<(3+v1)) | (1<<(6+v2)), p = v0*9+v1*3+v2
__constant__ unsigned c_need[27] = {
    73, 137, 265, 81, 145, 273, 97, 161, 289,
    74, 138, 266, 82, 146, 274, 98, 162, 290,
    76, 140, 268, 84, 148, 276, 100, 164, 292};

__global__ __launch_bounds__(256) void mask_kernel(
    const float* __restrict__ boards, unsigned long long* __restrict__ ws)
{
    __shared__ float sP[G][169];                           // padded 13x13 boards
    __shared__ __align__(16) unsigned short sMask[G][144]; // per-cell 9-bit masks

    const int tid = threadIdx.x;
    const size_t b0 = (size_t)blockIdx.x * G;

    // Phase 1: padded P (13x13) for G boards; all loads independent.
    #pragma unroll
    for (int it = 0; it < 6; ++it) {
        int idx = tid + it * 256;
        if (idx < G * 169) {
            int g = idx / 169;
            int pos = idx - g * 169;
            int pr = pos / 13, pc = pos % 13;
            bool ir = (pr >= 1) & (pr <= 11);
            bool jr = (pc >= 1) & (pc <= 11);
            float v;
            if (ir & jr)  v = boards[(b0 + g) * 121 + (pr - 1) * 11 + (pc - 1)];
            else if (jr)  v = 1.0f;    // top/bottom edge rows
            else if (ir)  v = -1.0f;   // left/right edge cols
            else          v = 0.0f;    // corners
            sP[g][pos] = v;
        }
    }
    __syncthreads();

    // Phase 2: per-cell masks (3 one-hot 3-bit fields; corner cells -> 0b111).
    #pragma unroll
    for (int it = 0; it < 5; ++it) {
        int idx = tid + it * 256;
        if (idx < G * 144) {
            int g = idx / 144;
            int cell = idx - g * 144;
            int r = cell / 12, c = cell % 12;
            const float* P = sP[g];
            int i0 = (int)P[r * 13 + c] + 1;        // a0 = P[r][c]
            int i1 = (int)P[r * 13 + c + 1] + 1;    // a1 = P[r][c+1]
            int i2 = (int)P[(r + 1) * 13 + c] + 1;  // a2 = P[r+1][c]
            unsigned m0 = (cell == 0)   ? 7u : (1u << i0);   // eq0 @ (0,0)
            unsigned m1 = (cell == 11)  ? 7u : (1u << i1);   // eq1 @ (0,11)
            unsigned m2 = (cell == 132) ? 7u : (1u << i2);   // eq2 @ (11,0)
            sMask[g][cell] = (unsigned short)(m0 | (m1 << 3) | (m2 << 6));
        }
    }
    __syncthreads();

    // Copy masks out: G*144 u16 = 2304 B = 144 x 16B, coalesced.
    if (tid < G * 18) {
        ((ulonglong2*)(ws + (size_t)blockIdx.x * (G * 36)))[tid] =
            ((const ulonglong2*)sMask)[tid];
    }
}

__global__ __launch_bounds__(256) void stream_kernel(
    const unsigned long long* __restrict__ masks, float* __restrict__ out)
{
    const int tid = threadIdx.x;
    const size_t b = blockIdx.x;
    const unsigned long long* mb = masks + b * 36;
    f4* outv = (f4*)out + b * 972;

    #pragma unroll
    for (int it = 0; it < 4; ++it) {
        int idx = tid + it * 256;
        if (idx < 972) {
            int p = idx / 36;             // magic-mul
            int cell4 = idx - p * 36;     // float4 group within the 144 cells
            unsigned need = c_need[p];
            unsigned long long m4 = mb[cell4];
            f4 o;
            o.x = (((unsigned)(m4)       & need) == need) ? 1.0f : 0.0f;
            o.y = (((unsigned)(m4 >> 16) & need) == need) ? 1.0f : 0.0f;
            o.z = (((unsigned)(m4 >> 32) & need) == need) ? 1.0f : 0.0f;
            o.w = (((unsigned)(m4 >> 48) & need) == need) ? 1.0f : 0.0f;
            outv[idx] = o;
        }
    }
}

extern "C" void kernel_launch(void* const* d_in, const int* in_sizes, int n_in,
                              void* d_out, int out_size, void* d_ws, size_t ws_size,
                              hipStream_t stream) {
    const float* boards = (const float*)d_in[0];
    float* out = (float*)d_out;
    unsigned long long* ws = (unsigned long long*)d_ws;
    mask_kernel<<<32768 / G, 256, 0, stream>>>(boards, ws);
    stream_kernel<<<32768, 256, 0, stream>>>(ws, out);
}

// Round 4
// 111.774 us; speedup vs baseline: 1.0627x; 1.0627x over previous
//
#include <hip/hip_runtime.h>

// Encode 11x11 hex boards -> (B, 27, 12, 12) one-hot pattern tensor.
// Store-BW-bound (509.6 MB out). Persistent kernel: 2048 blocks x 256 thr
// = 8192 waves fully resident, each wave independently handles 4 boards.
// No __syncthreads in the loop: wave-synchronous LDS only.

typedef float f4 __attribute__((ext_vector_type(4)));

#define NBLOCK 2048
#define BOARDS_PER_WAVE 4   // 32768 boards / 8192 waves

__global__ __launch_bounds__(256) void hex_encode_kernel(
    const float* __restrict__ boards, float* __restrict__ out)
{
    __shared__ float sP[4][176];                          // per-wave padded 13x13
    __shared__ __align__(8) unsigned short sMask[4][160]; // per-wave cell masks
    __shared__ unsigned sNeed[27];                        // pattern -> need bits

    const int tid = threadIdx.x;
    const int wave = tid >> 6;
    const int lane = tid & 63;

    if (tid < 27) {
        int v0 = tid / 9, v1 = (tid / 3) % 3, v2 = tid % 3;
        sNeed[tid] = (1u << v0) | (1u << (3 + v1)) | (1u << (6 + v2));
    }

    float* P = sP[wave];
    unsigned short* M = sMask[wave];

    // One-time: P edge/corner constants (never change across boards).
    #pragma unroll
    for (int s = 0; s < 3; ++s) {
        int j = lane + s * 64;
        if (j < 169) {
            int pr = j / 13, pc = j % 13;
            bool ir = (pr >= 1) & (pr <= 11);
            bool jr = (pc >= 1) & (pc <= 11);
            if (!(ir & jr))
                P[j] = jr ? 1.0f : (ir ? -1.0f : 0.0f);
        }
    }
    __syncthreads();  // one-time: sNeed visible to all waves

    const size_t wgid = (size_t)blockIdx.x * 4 + wave;
    const size_t b0 = wgid * BOARDS_PER_WAVE;

    // Prefetch board 0 into registers (lane i holds board[i], board[64+i]).
    const float* bp = boards + b0 * 121;
    float r0 = bp[lane];
    float r1 = (lane < 57) ? bp[64 + lane] : 0.0f;

    for (int k = 0; k < BOARDS_PER_WAVE; ++k) {
        const size_t b = b0 + k;

        // Interior of P from registers (vmcnt wait auto-inserted via reg dep).
        P[(1 + lane / 11) * 13 + 1 + lane % 11] = r0;
        if (lane < 57)
            P[(1 + (lane + 64) / 11) * 13 + 1 + (lane + 64) % 11] = r1;
        asm volatile("s_waitcnt lgkmcnt(0)" ::: "memory");
        __builtin_amdgcn_wave_barrier();

        // Per-cell 9-bit masks (3 one-hot fields; corner overrides -> 0b111).
        #pragma unroll
        for (int s = 0; s < 3; ++s) {
            int j = lane + s * 64;
            if (j < 144) {
                int r = j / 12, c = j - 12 * r;
                int i0 = (int)P[r * 13 + c] + 1;        // a0
                int i1 = (int)P[r * 13 + c + 1] + 1;    // a1
                int i2 = (int)P[(r + 1) * 13 + c] + 1;  // a2
                unsigned m0 = (j == 0)   ? 7u : (1u << i0);
                unsigned m1 = (j == 11)  ? 7u : (1u << i1);
                unsigned m2 = (j == 132) ? 7u : (1u << i2);
                M[j] = (unsigned short)(m0 | (m1 << 3) | (m2 << 6));
            }
        }
        asm volatile("s_waitcnt lgkmcnt(0)" ::: "memory");
        __builtin_amdgcn_wave_barrier();

        // Prefetch next board's registers; latency hides under store stream.
        if (k + 1 < BOARDS_PER_WAVE) {
            const float* np = boards + (b + 1) * 121;
            r0 = np[lane];
            r1 = (lane < 57) ? np[64 + lane] : 0.0f;
        }

        // Stream 972 float4 for this board, contiguous, plain stores.
        f4* outv = (f4*)out + b * 972;
        const unsigned long long* m64 = (const unsigned long long*)M;
        #pragma unroll 4
        for (int it = 0; it < 16; ++it) {
            int idx = lane + it * 64;
            if (idx < 972) {
                int p = idx / 36;             // pattern 0..26 (magic-mul)
                int cell4 = idx - p * 36;     // float4 group within 144 cells
                unsigned need = sNeed[p];
                unsigned long long m4 = m64[cell4];
                f4 o;
                o.x = (((unsigned)(m4)       & need) == need) ? 1.0f : 0.0f;
                o.y = (((unsigned)(m4 >> 16) & need) == need) ? 1.0f : 0.0f;
                o.z = (((unsigned)(m4 >> 32) & need) == need) ? 1.0f : 0.0f;
                o.w = (((unsigned)(m4 >> 48) & need) == need) ? 1.0f : 0.0f;
                outv[idx] = o;
            }
        }
        // Next iteration's M writes come after an lgkmcnt(0) that also drains
        // this stream's ds_reads (DS ops are in-order per wave) -> WAR safe.
    }
}

extern "C" void kernel_launch(void* const* d_in, const int* in_sizes, int n_in,
                              void* d_out, int out_size, void* d_ws, size_t ws_size,
                              hipStream_t stream) {
    const float* boards = (const float*)d_in[0];
    float* out = (float*)d_out;
    hex_encode_kernel<<<NBLOCK, 256, 0, stream>>>(boards, out);
}

// Round 5
// 106.632 us; speedup vs baseline: 1.1139x; 1.0482x over previous
//
#include <hip/hip_runtime.h>

// Encode 11x11 hex boards -> (B, 27, 12, 12) one-hot float32 tensor.
// Store-BW-bound: 509.6 MB out. Fill-kernel-shaped: one resident generation
// (2048 blocks = 8/CU), each block computes 16 boards' masks up front, then
// does ONE uninterrupted contiguous 243 KB store sweep (no barriers, no
// global loads, no per-board bookkeeping inside the store stream).

typedef float f4 __attribute__((ext_vector_type(4)));

#define G    16          // boards per block
#define NBLK 2048        // 32768 / G  -> exactly 8 blocks/CU, one generation

__global__ __launch_bounds__(256) void hex_encode_kernel(
    const float* __restrict__ boards, float* __restrict__ out)
{
    __shared__ float sP[G][176];                       // padded 13x13 per board
    __shared__ __align__(8) unsigned short sM[G][144]; // per-cell 9-bit masks
    __shared__ unsigned sNeed[32];                     // pattern -> need bits

    const int tid = threadIdx.x;
    const size_t b0 = (size_t)blockIdx.x * G;

    if (tid < 27) {
        int v0 = tid / 9, v1 = (tid / 3) % 3, v2 = tid % 3;
        sNeed[tid] = (1u << v0) | (1u << (3 + v1)) | (1u << (6 + v2));
    }

    // Phase 1: padded P (13x13) for all 16 boards. 16*169 = 2704 entries.
    // All global loads independent -> one latency exposure, once per block.
    #pragma unroll
    for (int it = 0; it < 11; ++it) {
        int idx = tid + it * 256;
        if (idx < G * 169) {
            int g = idx / 169;
            int pos = idx - g * 169;
            int pr = pos / 13, pc = pos % 13;
            bool ir = (pr >= 1) & (pr <= 11);
            bool jr = (pc >= 1) & (pc <= 11);
            float v;
            if (ir & jr)  v = boards[(b0 + g) * 121 + (pr - 1) * 11 + (pc - 1)];
            else if (jr)  v = 1.0f;    // top/bottom edge rows
            else if (ir)  v = -1.0f;   // left/right edge cols
            else          v = 0.0f;    // corners
            sP[g][pos] = v;
        }
    }
    __syncthreads();

    // Phase 2: per-cell 9-bit masks (3 one-hot 3-bit fields; the three
    // corner-override cells get a full 0b111 field). 16*144 = 2304.
    #pragma unroll
    for (int it = 0; it < 9; ++it) {
        int idx = tid + it * 256;
        if (idx < G * 144) {
            int g = idx / 144;
            int cell = idx - g * 144;
            int r = cell / 12, c = cell - 12 * r;
            const float* P = sP[g];
            int i0 = (int)P[r * 13 + c] + 1;        // a0 = P[r][c]
            int i1 = (int)P[r * 13 + c + 1] + 1;    // a1 = P[r][c+1]
            int i2 = (int)P[(r + 1) * 13 + c] + 1;  // a2 = P[r+1][c]
            unsigned m0 = (cell == 0)   ? 7u : (1u << i0);   // eq0 @ (0,0)
            unsigned m1 = (cell == 11)  ? 7u : (1u << i1);   // eq1 @ (0,11)
            unsigned m2 = (cell == 132) ? 7u : (1u << i2);   // eq2 @ (11,0)
            sM[g][cell] = (unsigned short)(m0 | (m1 << 3) | (m2 << 6));
        }
    }
    __syncthreads();

    // Phase 3: ONE contiguous sweep of 16*972 = 15552 float4 (243 KB).
    // No barriers, no global loads; 8-B conflict-free LDS reads only.
    f4* outv = (f4*)out + b0 * 972;
    const unsigned long long* m64 = (const unsigned long long*)sM;
    #pragma unroll 4
    for (int it = 0; it < 61; ++it) {
        int idx = tid + it * 256;
        if (idx < G * 972) {
            unsigned g = (unsigned)idx / 972u;       // magic-mul
            unsigned rem = (unsigned)idx - g * 972u;
            unsigned p = rem / 36u;                  // pattern 0..26
            unsigned cell4 = rem - p * 36u;          // float4 group in 144 cells
            unsigned need = sNeed[p];
            unsigned long long m4 = m64[g * 36 + cell4];
            f4 o;
            o.x = (((unsigned)(m4)       & need) == need) ? 1.0f : 0.0f;
            o.y = (((unsigned)(m4 >> 16) & need) == need) ? 1.0f : 0.0f;
            o.z = (((unsigned)(m4 >> 32) & need) == need) ? 1.0f : 0.0f;
            o.w = (((unsigned)(m4 >> 48) & need) == need) ? 1.0f : 0.0f;
            outv[idx] = o;
        }
    }
}

extern "C" void kernel_launch(void* const* d_in, const int* in_sizes, int n_in,
                              void* d_out, int out_size, void* d_ws, size_t ws_size,
                              hipStream_t stream) {
    const float* boards = (const float*)d_in[0];
    float* out = (float*)d_out;
    hex_encode_kernel<<<NBLK, 256, 0, stream>>>(boards, out);
}